// Round 11
// baseline (488.687 us; speedup 1.0000x reference)
//
#include <hip/hip_runtime.h>
#include <math.h>

#define B_ 2
#define S_ 2048
#define D_ 2048
#define H_ 16
#define QLORA 1536
#define KVLORA 512
#define DN 128
#define DR 64
#define DQK 192
#define DV 128
#define EPSF 1e-6f
#define SCALEF 0.07216878364870322f   // 192^-0.5

typedef short short8 __attribute__((ext_vector_type(8)));
typedef float float4v __attribute__((ext_vector_type(4)));

__device__ __forceinline__ unsigned short f2bf(float f) {
    union { float f; unsigned u; } x; x.f = f;
    unsigned r = x.u + 0x7fffu + ((x.u >> 16) & 1u);   // RNE
    return (unsigned short)(r >> 16);
}
__device__ __forceinline__ float bf2f(unsigned short u) {
    union { unsigned u; float f; } x; x.u = (unsigned)u << 16;
    return x.f;
}

// async global->LDS, 16B per lane; LDS dest = wave-uniform base + lane*16
#define GLD16(src, dst)                                                        \
    __builtin_amdgcn_global_load_lds(                                          \
        (const __attribute__((address_space(1))) void*)(src),                  \
        (__attribute__((address_space(3))) void*)(dst), 16, 0, 0)

// ---------------------------------------------------------------------------
// all fp32->bf16 conversions in ONE launch (6 ranges, if-chain)
// ---------------------------------------------------------------------------
__global__ __launch_bounds__(256) void conv_all(
        const float* __restrict__ s0, unsigned short* __restrict__ d0, long e0,
        const float* __restrict__ s1, unsigned short* __restrict__ d1, long e1,
        const float* __restrict__ s2, unsigned short* __restrict__ d2, long e2,
        const float* __restrict__ s3, unsigned short* __restrict__ d3, long e3,
        const float* __restrict__ s4, unsigned short* __restrict__ d4, long e4,
        const float* __restrict__ s5, unsigned short* __restrict__ d5) {
    long c = (long)blockIdx.x * 256 + threadIdx.x;   // 8-elem chunk index
    const float* src;
    unsigned short* dst;
    if      (c < e0) { src = s0; dst = d0; }
    else if (c < e1) { src = s1; dst = d1; c -= e0; }
    else if (c < e2) { src = s2; dst = d2; c -= e1; }
    else if (c < e3) { src = s3; dst = d3; c -= e2; }
    else if (c < e4) { src = s4; dst = d4; c -= e3; }
    else             { src = s5; dst = d5; c -= e4; }
    const float* p = src + c * 8;
    float4 a = *(const float4*)(p);
    float4 b = *(const float4*)(p + 4);
    union { short8 v; unsigned short u[8]; } t;
    t.u[0] = f2bf(a.x); t.u[1] = f2bf(a.y); t.u[2] = f2bf(a.z); t.u[3] = f2bf(a.w);
    t.u[4] = f2bf(b.x); t.u[5] = f2bf(b.y); t.u[6] = f2bf(b.z); t.u[7] = f2bf(b.w);
    *(short8*)&dst[c * 8] = t.v;
}

// ---------------------------------------------------------------------------
// bf16 MFMA GEMM:  C[M,N] = A[M,K] @ W[N,K]^T; OT = float or ushort(bf16) out.
// ---------------------------------------------------------------------------
#define GBM 128
#define GBN 128
#define GBK 64

template <typename OT>
__global__ __launch_bounds__(256) void gemm_t(const unsigned short* __restrict__ A,
                                              const unsigned short* __restrict__ W,
                                              OT* __restrict__ C,
                                              int M, int N, int K) {
    __shared__ unsigned short As[GBM * GBK];   // 16384 B
    __shared__ unsigned short Ws[GBN * GBK];   // 16384 B

    const int tid = threadIdx.x;
    const int w = tid >> 6, lane = tid & 63;
    const int l16 = lane & 15, quad = lane >> 4;
    const int wm = (w >> 1) * 64, wn = (w & 1) * 64;
    const int row0 = blockIdx.y * GBM, col0 = blockIdx.x * GBN;

    const int rL  = lane >> 3;
    const int c8g = (lane & 7) ^ rL;
    const int swzk[2] = { (((0 * 4) + quad) ^ (l16 & 7)) * 8,
                          (((1 * 4) + quad) ^ (l16 & 7)) * 8 };

    const float4v zf = {0.f, 0.f, 0.f, 0.f};
    float4v acc[4][4] = {{zf, zf, zf, zf}, {zf, zf, zf, zf},
                         {zf, zf, zf, zf}, {zf, zf, zf, zf}};

    for (int k0 = 0; k0 < K; k0 += GBK) {
        __syncthreads();
#pragma unroll
        for (int j = 0; j < 4; ++j) {
            const int ch = w * 4 + j;
            const int r = ch * 8 + rL;
            GLD16(&A[(size_t)(row0 + r) * K + k0 + c8g * 8], &As[ch * 512]);
            GLD16(&W[(size_t)(col0 + r) * K + k0 + c8g * 8], &Ws[ch * 512]);
        }
        __syncthreads();

#pragma unroll
        for (int kk = 0; kk < 2; ++kk) {
            const int swz = swzk[kk];
            short8 af[4], bf[4];
#pragma unroll
            for (int mi = 0; mi < 4; ++mi)
                af[mi] = *(const short8*)&As[(wm + mi * 16 + l16) * GBK + swz];
#pragma unroll
            for (int ni = 0; ni < 4; ++ni)
                bf[ni] = *(const short8*)&Ws[(wn + ni * 16 + l16) * GBK + swz];
#pragma unroll
            for (int mi = 0; mi < 4; ++mi)
#pragma unroll
                for (int ni = 0; ni < 4; ++ni)
                    acc[mi][ni] = __builtin_amdgcn_mfma_f32_16x16x32_bf16(af[mi], bf[ni], acc[mi][ni], 0, 0, 0);
        }
    }

#pragma unroll
    for (int mi = 0; mi < 4; ++mi)
#pragma unroll
        for (int ni = 0; ni < 4; ++ni)
#pragma unroll
            for (int r = 0; r < 4; ++r) {
                size_t idx = (size_t)(row0 + wm + mi * 16 + quad * 4 + r) * N + col0 + wn + ni * 16 + l16;
                if constexpr (sizeof(OT) == 2) C[idx] = f2bf(acc[mi][ni][r]);
                else                           C[idx] = acc[mi][ni][r];
            }
}

// ---------------------------------------------------------------------------
__global__ __launch_bounds__(256) void rmsnorm_b(const float* __restrict__ X,
                                                 const float* __restrict__ w,
                                                 unsigned short* __restrict__ Y,
                                                 int n, int ld) {
    __shared__ float tmp[4];
    const int row = blockIdx.x;
    const int tid = threadIdx.x;
    const float* x = X + (size_t)row * ld;

    float ss = 0.f;
    for (int c = tid; c < n; c += 256) {
        float v = x[c];
        ss = fmaf(v, v, ss);
    }
#pragma unroll
    for (int off = 32; off; off >>= 1) ss += __shfl_xor(ss, off, 64);
    if ((tid & 63) == 0) tmp[tid >> 6] = ss;
    __syncthreads();
    ss = tmp[0] + tmp[1] + tmp[2] + tmp[3];
    float r = rsqrtf(ss / (float)n + EPSF);

    for (int c = tid; c < n; c += 256)
        Y[(size_t)row * n + c] = f2bf(x[c] * r * w[c]);
}

// ---------------------------------------------------------------------------
__global__ __launch_bounds__(256) void kv_post(const float* __restrict__ KV,
                                               const float* __restrict__ w,
                                               const float* __restrict__ fc,
                                               unsigned short* __restrict__ kvcb,
                                               float* __restrict__ kpe,
                                               int ldkv) {
    __shared__ float tmp[4];
    const int row = blockIdx.x;
    const int s = row & (S_ - 1);
    const int tid = threadIdx.x;
    const float* kv = KV + (size_t)row * ldkv;

    float ss = 0.f;
#pragma unroll
    for (int c = tid; c < KVLORA; c += 256) {
        float v = kv[c];
        ss = fmaf(v, v, ss);
    }
#pragma unroll
    for (int off = 32; off; off >>= 1) ss += __shfl_xor(ss, off, 64);
    if ((tid & 63) == 0) tmp[tid >> 6] = ss;
    __syncthreads();
    ss = tmp[0] + tmp[1] + tmp[2] + tmp[3];
    float r = rsqrtf(ss / (float)KVLORA + EPSF);

#pragma unroll
    for (int c = tid; c < KVLORA; c += 256)
        kvcb[(size_t)row * KVLORA + c] = f2bf(kv[c] * r * w[c]);

    if (tid < 32) {
        int i = tid;
        float c0 = fc[(s * 32 + i) * 2 + 0];
        float s0 = fc[(s * 32 + i) * 2 + 1];
        float x0 = kv[KVLORA + 2 * i];
        float x1 = kv[KVLORA + 2 * i + 1];
        kpe[(size_t)row * DR + 2 * i]     = x0 * c0 - x1 * s0;
        kpe[(size_t)row * DR + 2 * i + 1] = x0 * s0 + x1 * c0;
    }
}

// ---------------------------------------------------------------------------
// fused pack: blockIdx.x < NPK -> pack_k chunks; else pack_vt tiles.
// (kpe lives outside Vt's region now -> no ordering constraint)
// ---------------------------------------------------------------------------
#define NPK (B_ * H_ * S_ * (DQK / 8) / 256)   // 6144 blocks for pack_k

__global__ __launch_bounds__(256) void pack_kv(const unsigned short* __restrict__ kvbb,
                                               const float* __restrict__ kpe,
                                               unsigned short* __restrict__ Kbf,
                                               unsigned short* __restrict__ Vt) {
    __shared__ unsigned short T[DV][72];
    const int tid = threadIdx.x;
    if ((int)blockIdx.x < NPK) {
        const int c = blockIdx.x * 256 + tid;
        const int d8 = c % (DQK / 8);
        const int hs = c / (DQK / 8);
        const int s  = hs % S_;
        const int bh = hs / S_;
        const int b  = bh / H_;
        const int h  = bh % H_;
        const int d  = d8 * 8;
        const int row = b * S_ + s;

        short8 v;
        if (d < DN) {
            v = *(const short8*)&kvbb[(size_t)row * (H_ * 256) + h * 256 + d];
        } else {
            const float* src = kpe + (size_t)row * DR + (d - DN);
            float4 a = *(const float4*)(src);
            float4 bb = *(const float4*)(src + 4);
            union { short8 v; unsigned short u[8]; } t;
            t.u[0] = f2bf(a.x);  t.u[1] = f2bf(a.y);  t.u[2] = f2bf(a.z);  t.u[3] = f2bf(a.w);
            t.u[4] = f2bf(bb.x); t.u[5] = f2bf(bb.y); t.u[6] = f2bf(bb.z); t.u[7] = f2bf(bb.w);
            v = t.v;
        }
        *(short8*)&Kbf[(size_t)c * 8] = v;
    } else {
        const int id = blockIdx.x - NPK;        // 0..1023
        const int st = id & 31;                 // seq tile
        const int bh = id >> 5;                 // b*H+h
        const int b = bh >> 4, h = bh & 15;
        const int s0 = st * 64;

        for (int c = tid; c < 64 * 16; c += 256) {
            int sp = c >> 4, ch = c & 15;
            short8 v = *(const short8*)&kvbb[(size_t)(b * S_ + s0 + sp) * (H_ * 256) + h * 256 + DN + ch * 8];
            union { short8 v; unsigned short u[8]; } t; t.v = v;
            int dv = ch * 8;
#pragma unroll
            for (int e = 0; e < 8; ++e) T[dv + e][sp] = t.u[e];
        }
        __syncthreads();
        for (int c = tid; c < 128 * 8; c += 256) {
            int dv = c >> 3, ch = c & 7;
            *(short8*)&Vt[((size_t)bh * DV + dv) * S_ + s0 + ch * 8] = *(short8*)&T[dv][ch * 8];
        }
    }
}

// ---------------------------------------------------------------------------
// Split-K MFMA flash attention (causal), max-free softmax -> partials are
// additive: o = sum(o_i) / sum(l_i). Grid: x = bh, y = unit (48):
//   u<16:  q-tile u, full K range [0,u]      -> direct bf16 write
//   u>=16: q-tile 16+(u-16)/2, half K range  -> fp32 partial to scratch
// ---------------------------------------------------------------------------
#define KROW 200    // 192+8 bf16 pad
#define VROW 72     // 64+8
#define PROW 72
#define NQT 32

__global__ __launch_bounds__(256, 2) void flash_split(const unsigned short* __restrict__ Qb,
                                                      const float* __restrict__ fc,
                                                      const unsigned short* __restrict__ Kbf,
                                                      const unsigned short* __restrict__ Vt,
                                                      unsigned short* __restrict__ Ob,
                                                      float* __restrict__ Opart,
                                                      float* __restrict__ Lpart) {
    __shared__ unsigned short Ks[64][KROW];     // 25600 B
    __shared__ unsigned short Vs[DV][VROW];     // 18432 B
    __shared__ unsigned short Ps[4][16][PROW];  //  9216 B

    const int bh = blockIdx.x;                  // b*H+h (fast dim -> XCD locality)
    const int u  = blockIdx.y;                  // work unit
    const int b = bh >> 4, h = bh & 15;
    const int tid = threadIdx.x;
    const int w = tid >> 6, lane = tid & 63;
    const int l16 = lane & 15, quad = lane >> 4;

    int qt, kt0, kt1, slot;
    bool partial;
    if (u < 16) { qt = u; kt0 = 0; kt1 = u + 1; partial = false; slot = 0; }
    else {
        int idx = u - 16;
        qt = 16 + (idx >> 1);
        slot = idx & 1;
        int nt = qt + 1, mid = nt >> 1;
        kt0 = slot ? mid : 0;
        kt1 = slot ? nt : mid;
        partial = true;
    }
    const int q0 = qt * 64;

    const unsigned short* Kg = Kbf + (size_t)bh * S_ * DQK;
    const unsigned short* Vg = Vt + (size_t)bh * DV * S_;

    const int s = q0 + w * 16 + l16;            // this lane's q row (seq pos)

    // Q A-frags from bf16 q, RoPE fused for d >= 128 (pairs are lane-local)
    short8 a_q[6];
    {
        const unsigned short* qrow = Qb + (size_t)(b * S_ + s) * (H_ * DQK) + h * DQK;
#pragma unroll
        for (int i = 0; i < 6; ++i) {
            short8 t = *(const short8*)&qrow[i * 32 + quad * 8];
            if (i >= 4) {
                union { short8 v; unsigned short u[8]; } x; x.v = t;
#pragma unroll
                for (int j = 0; j < 4; ++j) {
                    int ip = (i - 4) * 16 + quad * 4 + j;
                    float c0 = fc[(s * 32 + ip) * 2 + 0];
                    float s0 = fc[(s * 32 + ip) * 2 + 1];
                    float x0 = bf2f(x.u[2 * j]);
                    float x1 = bf2f(x.u[2 * j + 1]);
                    x.u[2 * j]     = f2bf(x0 * c0 - x1 * s0);
                    x.u[2 * j + 1] = f2bf(x0 * s0 + x1 * c0);
                }
                t = x.v;
            }
            a_q[i] = t;
        }
    }

    const float4v zf = {0.f, 0.f, 0.f, 0.f};
    float4v o_acc[8] = {zf, zf, zf, zf, zf, zf, zf, zf};
    float l_r[4] = {0.f, 0.f, 0.f, 0.f};

    // preload tile kt0
    short8 ldK[6], ldV[4];
#pragma unroll
    for (int i = 0; i < 6; ++i) {
        int c = tid + i * 256;
        int r = c / 24, cc = c % 24;
        ldK[i] = *(const short8*)&Kg[(size_t)(kt0 * 64 + r) * DQK + cc * 8];
    }
#pragma unroll
    for (int i = 0; i < 4; ++i) {
        int c = tid + i * 256;
        int r = c >> 3, cc = c & 7;
        ldV[i] = *(const short8*)&Vg[(size_t)r * S_ + kt0 * 64 + cc * 8];
    }

    for (int kt = kt0; kt < kt1; ++kt) {
        const int kbase = kt * 64;
        __syncthreads();
#pragma unroll
        for (int i = 0; i < 6; ++i) {
            int c = tid + i * 256;
            int r = c / 24, cc = c % 24;
            *(short8*)&Ks[r][cc * 8] = ldK[i];
        }
#pragma unroll
        for (int i = 0; i < 4; ++i) {
            int c = tid + i * 256;
            int r = c >> 3, cc = c & 7;
            *(short8*)&Vs[r][cc * 8] = ldV[i];
        }
        if (kt + 1 < kt1) {
            const int kb2 = kbase + 64;
#pragma unroll
            for (int i = 0; i < 6; ++i) {
                int c = tid + i * 256;
                int r = c / 24, cc = c % 24;
                ldK[i] = *(const short8*)&Kg[(size_t)(kb2 + r) * DQK + cc * 8];
            }
#pragma unroll
            for (int i = 0; i < 4; ++i) {
                int c = tid + i * 256;
                int r = c >> 3, cc = c & 7;
                ldV[i] = *(const short8*)&Vg[(size_t)r * S_ + kb2 + cc * 8];
            }
        }
        __syncthreads();

        // QK^T
        float4v sc[4] = {zf, zf, zf, zf};
#pragma unroll
        for (int kg = 0; kg < 4; ++kg) {
#pragma unroll
            for (int i = 0; i < 6; ++i) {
                short8 bk = *(const short8*)&Ks[kg * 16 + l16][i * 32 + quad * 8];
                sc[kg] = __builtin_amdgcn_mfma_f32_16x16x32_bf16(a_q[i], bk, sc[kg], 0, 0, 0);
            }
        }

        // max-free softmax; mask only on the diagonal tile
        const bool diag = (kt == qt);
#pragma unroll
        for (int kg = 0; kg < 4; ++kg) {
            int key = kbase + kg * 16 + l16;
#pragma unroll
            for (int r = 0; r < 4; ++r) {
                float sv = sc[kg][r] * SCALEF;
                if (diag && key > q0 + w * 16 + quad * 4 + r) sv = -1e30f;
                float p = __expf(sv);
                l_r[r] += p;
                Ps[w][quad * 4 + r][kg * 16 + l16] = f2bf(p);
            }
        }

        __syncthreads();

        // PV
#pragma unroll
        for (int kc = 0; kc < 2; ++kc) {
            short8 pa = *(const short8*)&Ps[w][l16][kc * 32 + quad * 8];
#pragma unroll
            for (int dvt = 0; dvt < 8; ++dvt) {
                short8 vb = *(const short8*)&Vs[dvt * 16 + l16][kc * 32 + quad * 8];
                o_acc[dvt] = __builtin_amdgcn_mfma_f32_16x16x32_bf16(pa, vb, o_acc[dvt], 0, 0, 0);
            }
        }
    }

    // lane-reduce l across the 16 key-lanes
#pragma unroll
    for (int r = 0; r < 4; ++r) {
        float t = l_r[r];
        t += __shfl_xor(t, 1);
        t += __shfl_xor(t, 2);
        t += __shfl_xor(t, 4);
        t += __shfl_xor(t, 8);
        l_r[r] = t;
    }

    if (!partial) {
#pragma unroll
        for (int r = 0; r < 4; ++r) {
            float inv = 1.f / l_r[r];
            int row = q0 + w * 16 + quad * 4 + r;
            unsigned short* op = Ob + (size_t)(b * S_ + row) * (H_ * DV) + h * DV;
#pragma unroll
            for (int dvt = 0; dvt < 8; ++dvt)
                op[dvt * 16 + l16] = f2bf(o_acc[dvt][r] * inv);
        }
    } else {
        const size_t sb = ((size_t)(bh * 16 + (qt - 16)) * 2 + slot);
        float* ob = Opart + sb * 8192;
#pragma unroll
        for (int r = 0; r < 4; ++r) {
            int row = w * 16 + quad * 4 + r;
#pragma unroll
            for (int dvt = 0; dvt < 8; ++dvt)
                ob[(size_t)row * DV + dvt * 16 + l16] = o_acc[dvt][r];
            if (l16 == 0) Lpart[sb * 64 + row] = l_r[r];
        }
    }
}

// ---------------------------------------------------------------------------
// combine split partials: o = (o0+o1)/(l0+l1) -> bf16 attn
// ---------------------------------------------------------------------------
__global__ __launch_bounds__(256) void norm_comb(const float* __restrict__ Opart,
                                                 const float* __restrict__ Lpart,
                                                 unsigned short* __restrict__ Ob) {
    __shared__ float ls[64];
    const int t = blockIdx.x;          // bh*16 + (qt-16)
    const int bh = t >> 4, j = t & 15;
    const int qt = 16 + j;
    const int b = bh >> 4, h = bh & 15;
    const int tid = threadIdx.x;
    const size_t ob0 = (size_t)t * 2 * 8192, ob1 = ob0 + 8192;
    const size_t lb0 = (size_t)t * 2 * 64, lb1 = lb0 + 64;

    if (tid < 64) ls[tid] = Lpart[lb0 + tid] + Lpart[lb1 + tid];
    __syncthreads();

    for (int idx = tid; idx < 64 * DV; idx += 256) {
        int row = idx >> 7, col = idx & 127;
        float o = Opart[ob0 + idx] + Opart[ob1 + idx];
        Ob[(size_t)(b * S_ + qt * 64 + row) * (H_ * DV) + h * DV + col] = f2bf(o / ls[row]);
    }
}

// ---------------------------------------------------------------------------
extern "C" void kernel_launch(void* const* d_in, const int* in_sizes, int n_in,
                              void* d_out, int out_size, void* d_ws, size_t ws_size,
                              hipStream_t stream) {
    const float* x    = (const float*)d_in[0];
    const float* fc   = (const float*)d_in[1];
    const float* Wqa  = (const float*)d_in[2];
    const float* qlw  = (const float*)d_in[3];
    const float* Wqb  = (const float*)d_in[4];
    const float* Wkva = (const float*)d_in[5];
    const float* kvw  = (const float*)d_in[6];
    const float* Wkvb = (const float*)d_in[7];
    const float* Wo   = (const float*)d_in[8];
    float* out = (float*)d_out;

    const int M = B_ * S_;                 // 4096
    const int NQKV = QLORA + 640;          // 2176
    char* wsb = (char*)d_ws;

    // R1 (50331648 B): qb bf16 (25165824) + Wob (8388608) + kpe (1048576)
    unsigned short* qb  = (unsigned short*)wsb;
    unsigned short* Wob = (unsigned short*)(wsb + 25165824);
    float*          kpe = (float*)(wsb + 33554432);
    // R2 (67108864 B)
    char* R2 = wsb + 50331648;
    float*          qlkv  = (float*)R2;                          // 35651584
    unsigned short* xb    = (unsigned short*)(R2 + 35651584);    // 16777216
    unsigned short* Wcat  = (unsigned short*)(R2 + 52428800);    //  8912896
    unsigned short* kvbb  = (unsigned short*)R2;                 // 33554432 (after qlkv dead)
    unsigned short* attnb = (unsigned short*)R2;                 // 16777216 (after packs)
    float*          Opart = (float*)(R2 + 16777216);             // 33554432 (flash scratch)
    float*          Lpart = (float*)(R2 + 50331648);             //   262144
    // R3 (25165824 B)
    char* R3 = R2 + 67108864;
    unsigned short* qlatb = (unsigned short*)R3;                 // 12582912
    unsigned short* Wqbb  = (unsigned short*)(R3 + 12582912);    //  9437184
    unsigned short* Kbf   = (unsigned short*)R3;                 // 25165824 (after q-gemm)
    // R4 (16777216 B)
    char* R4 = R3 + 25165824;
    unsigned short* kvcb  = (unsigned short*)R4;                 //  4194304
    unsigned short* Wkvbb = (unsigned short*)(R4 + 4194304);     //  4194304
    unsigned short* Vt    = (unsigned short*)R4;                 // 16777216 (after kvb-gemm)

    // 0) single mega-conversion: x, Wqa, Wkva, Wqb, Wkvb, Wo
    {
        const long e0 = 1048576;           // x      (M*D/8)
        const long e1 = e0 + 393216;       // Wqa
        const long e2 = e1 + 147456;       // Wkva
        const long e3 = e2 + 589824;       // Wqb
        const long e4 = e3 + 262144;       // Wkvb
        const long tot = e4 + 524288;      // Wo
        conv_all<<<(int)(tot / 256), 256, 0, stream>>>(
            x, xb, e0,
            Wqa, Wcat, e1,
            Wkva, Wcat + (size_t)QLORA * D_, e2,
            Wqb, Wqbb, e3,
            Wkvb, Wkvbb, e4,
            Wo, Wob);
    }

    // 1) merged: qlkv = xb @ Wcat^T
    gemm_t<float><<<dim3(NQKV / GBN, M / GBM), 256, 0, stream>>>(xb, Wcat, qlkv, M, NQKV, D_);

    // 2) norms (emit bf16) + k_pe rope
    rmsnorm_b<<<M, 256, 0, stream>>>(qlkv, qlw, qlatb, QLORA, NQKV);
    kv_post<<<M, 256, 0, stream>>>(qlkv + QLORA, kvw, fc, kvcb, kpe, NQKV);

    // 3) qb = qlatb @ Wqbb^T (bf16; RoPE fused into flash) ; kvbb = kvcb @ Wkvbb^T
    gemm_t<unsigned short><<<dim3(H_ * DQK / GBN, M / GBM), 256, 0, stream>>>(qlatb, Wqbb, qb, M, H_ * DQK, QLORA);
    gemm_t<unsigned short><<<dim3(H_ * 256 / GBN, M / GBM), 256, 0, stream>>>(kvcb, Wkvbb, kvbb, M, H_ * 256, KVLORA);

    // 4) fused pack K + V^T (no ordering constraint: kpe is outside Vt region)
    pack_kv<<<NPK + 1024, 256, 0, stream>>>(kvbb, kpe, Kbf, Vt);

    // 5) split-K flash (x = bh for XCD L2 locality, y = 48 work units)
    flash_split<<<dim3(B_ * H_, 48), 256, 0, stream>>>(qb, fc, Kbf, Vt, attnb, Opart, Lpart);

    // 5b) combine partials for q-tiles 16..31
    norm_comb<<<B_ * H_ * 16, 256, 0, stream>>>(Opart, Lpart, attnb);

    // 6) out = attnb @ Wob^T
    gemm_t<float><<<dim3(D_ / GBN, M / GBM), 256, 0, stream>>>(attnb, Wob, out, M, D_, D_);
}

// Round 12
// 459.205 us; speedup vs baseline: 1.0642x; 1.0642x over previous
//
#include <hip/hip_runtime.h>
#include <math.h>

#define B_ 2
#define S_ 2048
#define D_ 2048
#define H_ 16
#define QLORA 1536
#define KVLORA 512
#define DN 128
#define DR 64
#define DQK 192
#define DV 128
#define EPSF 1e-6f
#define SCALEF 0.07216878364870322f   // 192^-0.5

typedef short short8 __attribute__((ext_vector_type(8)));
typedef float float4v __attribute__((ext_vector_type(4)));

__device__ __forceinline__ unsigned short f2bf(float f) {
    union { float f; unsigned u; } x; x.f = f;
    unsigned r = x.u + 0x7fffu + ((x.u >> 16) & 1u);   // RNE
    return (unsigned short)(r >> 16);
}
__device__ __forceinline__ float bf2f(unsigned short u) {
    union { unsigned u; float f; } x; x.u = (unsigned)u << 16;
    return x.f;
}

// async global->LDS, 16B per lane; LDS dest = wave-uniform base + lane*16
#define GLD16(src, dst)                                                        \
    __builtin_amdgcn_global_load_lds(                                          \
        (const __attribute__((address_space(1))) void*)(src),                  \
        (__attribute__((address_space(3))) void*)(dst), 16, 0, 0)

// ---------------------------------------------------------------------------
// all fp32->bf16 conversions in ONE launch (6 ranges, if-chain)
// ---------------------------------------------------------------------------
__global__ __launch_bounds__(256) void conv_all(
        const float* __restrict__ s0, unsigned short* __restrict__ d0, long e0,
        const float* __restrict__ s1, unsigned short* __restrict__ d1, long e1,
        const float* __restrict__ s2, unsigned short* __restrict__ d2, long e2,
        const float* __restrict__ s3, unsigned short* __restrict__ d3, long e3,
        const float* __restrict__ s4, unsigned short* __restrict__ d4, long e4,
        const float* __restrict__ s5, unsigned short* __restrict__ d5) {
    long c = (long)blockIdx.x * 256 + threadIdx.x;   // 8-elem chunk index
    const float* src;
    unsigned short* dst;
    if      (c < e0) { src = s0; dst = d0; }
    else if (c < e1) { src = s1; dst = d1; c -= e0; }
    else if (c < e2) { src = s2; dst = d2; c -= e1; }
    else if (c < e3) { src = s3; dst = d3; c -= e2; }
    else if (c < e4) { src = s4; dst = d4; c -= e3; }
    else             { src = s5; dst = d5; c -= e4; }
    const float* p = src + c * 8;
    float4 a = *(const float4*)(p);
    float4 b = *(const float4*)(p + 4);
    union { short8 v; unsigned short u[8]; } t;
    t.u[0] = f2bf(a.x); t.u[1] = f2bf(a.y); t.u[2] = f2bf(a.z); t.u[3] = f2bf(a.w);
    t.u[4] = f2bf(b.x); t.u[5] = f2bf(b.y); t.u[6] = f2bf(b.z); t.u[7] = f2bf(b.w);
    *(short8*)&dst[c * 8] = t.v;
}

// ---------------------------------------------------------------------------
// bf16 MFMA GEMM:  C[M,N] = A[M,K] @ W[N,K]^T; OT = float or ushort(bf16) out.
// ---------------------------------------------------------------------------
#define GBM 128
#define GBN 128
#define GBK 64

template <typename OT>
__global__ __launch_bounds__(256) void gemm_t(const unsigned short* __restrict__ A,
                                              const unsigned short* __restrict__ W,
                                              OT* __restrict__ C,
                                              int M, int N, int K) {
    __shared__ unsigned short As[GBM * GBK];   // 16384 B
    __shared__ unsigned short Ws[GBN * GBK];   // 16384 B

    const int tid = threadIdx.x;
    const int w = tid >> 6, lane = tid & 63;
    const int l16 = lane & 15, quad = lane >> 4;
    const int wm = (w >> 1) * 64, wn = (w & 1) * 64;
    const int row0 = blockIdx.y * GBM, col0 = blockIdx.x * GBN;

    const int rL  = lane >> 3;
    const int c8g = (lane & 7) ^ rL;
    const int swzk[2] = { (((0 * 4) + quad) ^ (l16 & 7)) * 8,
                          (((1 * 4) + quad) ^ (l16 & 7)) * 8 };

    const float4v zf = {0.f, 0.f, 0.f, 0.f};
    float4v acc[4][4] = {{zf, zf, zf, zf}, {zf, zf, zf, zf},
                         {zf, zf, zf, zf}, {zf, zf, zf, zf}};

    for (int k0 = 0; k0 < K; k0 += GBK) {
        __syncthreads();
#pragma unroll
        for (int j = 0; j < 4; ++j) {
            const int ch = w * 4 + j;
            const int r = ch * 8 + rL;
            GLD16(&A[(size_t)(row0 + r) * K + k0 + c8g * 8], &As[ch * 512]);
            GLD16(&W[(size_t)(col0 + r) * K + k0 + c8g * 8], &Ws[ch * 512]);
        }
        __syncthreads();

#pragma unroll
        for (int kk = 0; kk < 2; ++kk) {
            const int swz = swzk[kk];
            short8 af[4], bf[4];
#pragma unroll
            for (int mi = 0; mi < 4; ++mi)
                af[mi] = *(const short8*)&As[(wm + mi * 16 + l16) * GBK + swz];
#pragma unroll
            for (int ni = 0; ni < 4; ++ni)
                bf[ni] = *(const short8*)&Ws[(wn + ni * 16 + l16) * GBK + swz];
#pragma unroll
            for (int mi = 0; mi < 4; ++mi)
#pragma unroll
                for (int ni = 0; ni < 4; ++ni)
                    acc[mi][ni] = __builtin_amdgcn_mfma_f32_16x16x32_bf16(af[mi], bf[ni], acc[mi][ni], 0, 0, 0);
        }
    }

#pragma unroll
    for (int mi = 0; mi < 4; ++mi)
#pragma unroll
        for (int ni = 0; ni < 4; ++ni)
#pragma unroll
            for (int r = 0; r < 4; ++r) {
                size_t idx = (size_t)(row0 + wm + mi * 16 + quad * 4 + r) * N + col0 + wn + ni * 16 + l16;
                if constexpr (sizeof(OT) == 2) C[idx] = f2bf(acc[mi][ni][r]);
                else                           C[idx] = acc[mi][ni][r];
            }
}

// ---------------------------------------------------------------------------
__global__ __launch_bounds__(256) void rmsnorm_b(const float* __restrict__ X,
                                                 const float* __restrict__ w,
                                                 unsigned short* __restrict__ Y,
                                                 int n, int ld) {
    __shared__ float tmp[4];
    const int row = blockIdx.x;
    const int tid = threadIdx.x;
    const float* x = X + (size_t)row * ld;

    float ss = 0.f;
    for (int c = tid; c < n; c += 256) {
        float v = x[c];
        ss = fmaf(v, v, ss);
    }
#pragma unroll
    for (int off = 32; off; off >>= 1) ss += __shfl_xor(ss, off, 64);
    if ((tid & 63) == 0) tmp[tid >> 6] = ss;
    __syncthreads();
    ss = tmp[0] + tmp[1] + tmp[2] + tmp[3];
    float r = rsqrtf(ss / (float)n + EPSF);

    for (int c = tid; c < n; c += 256)
        Y[(size_t)row * n + c] = f2bf(x[c] * r * w[c]);
}

// ---------------------------------------------------------------------------
__global__ __launch_bounds__(256) void kv_post(const float* __restrict__ KV,
                                               const float* __restrict__ w,
                                               const float* __restrict__ fc,
                                               unsigned short* __restrict__ kvcb,
                                               float* __restrict__ kpe,
                                               int ldkv) {
    __shared__ float tmp[4];
    const int row = blockIdx.x;
    const int s = row & (S_ - 1);
    const int tid = threadIdx.x;
    const float* kv = KV + (size_t)row * ldkv;

    float ss = 0.f;
#pragma unroll
    for (int c = tid; c < KVLORA; c += 256) {
        float v = kv[c];
        ss = fmaf(v, v, ss);
    }
#pragma unroll
    for (int off = 32; off; off >>= 1) ss += __shfl_xor(ss, off, 64);
    if ((tid & 63) == 0) tmp[tid >> 6] = ss;
    __syncthreads();
    ss = tmp[0] + tmp[1] + tmp[2] + tmp[3];
    float r = rsqrtf(ss / (float)KVLORA + EPSF);

#pragma unroll
    for (int c = tid; c < KVLORA; c += 256)
        kvcb[(size_t)row * KVLORA + c] = f2bf(kv[c] * r * w[c]);

    if (tid < 32) {
        int i = tid;
        float c0 = fc[(s * 32 + i) * 2 + 0];
        float s0 = fc[(s * 32 + i) * 2 + 1];
        float x0 = kv[KVLORA + 2 * i];
        float x1 = kv[KVLORA + 2 * i + 1];
        kpe[(size_t)row * DR + 2 * i]     = x0 * c0 - x1 * s0;
        kpe[(size_t)row * DR + 2 * i + 1] = x0 * s0 + x1 * c0;
    }
}

// ---------------------------------------------------------------------------
// fused pack: blockIdx.x < NPK -> pack_k chunks; else pack_vt tiles.
// ---------------------------------------------------------------------------
#define NPK (B_ * H_ * S_ * (DQK / 8) / 256)   // 6144 blocks for pack_k

__global__ __launch_bounds__(256) void pack_kv(const unsigned short* __restrict__ kvbb,
                                               const float* __restrict__ kpe,
                                               unsigned short* __restrict__ Kbf,
                                               unsigned short* __restrict__ Vt) {
    __shared__ unsigned short T[DV][72];
    const int tid = threadIdx.x;
    if ((int)blockIdx.x < NPK) {
        const int c = blockIdx.x * 256 + tid;
        const int d8 = c % (DQK / 8);
        const int hs = c / (DQK / 8);
        const int s  = hs % S_;
        const int bh = hs / S_;
        const int b  = bh / H_;
        const int h  = bh % H_;
        const int d  = d8 * 8;
        const int row = b * S_ + s;

        short8 v;
        if (d < DN) {
            v = *(const short8*)&kvbb[(size_t)row * (H_ * 256) + h * 256 + d];
        } else {
            const float* src = kpe + (size_t)row * DR + (d - DN);
            float4 a = *(const float4*)(src);
            float4 bb = *(const float4*)(src + 4);
            union { short8 v; unsigned short u[8]; } t;
            t.u[0] = f2bf(a.x);  t.u[1] = f2bf(a.y);  t.u[2] = f2bf(a.z);  t.u[3] = f2bf(a.w);
            t.u[4] = f2bf(bb.x); t.u[5] = f2bf(bb.y); t.u[6] = f2bf(bb.z); t.u[7] = f2bf(bb.w);
            v = t.v;
        }
        *(short8*)&Kbf[(size_t)c * 8] = v;
    } else {
        const int id = blockIdx.x - NPK;        // 0..1023
        const int st = id & 31;                 // seq tile
        const int bh = id >> 5;                 // b*H+h
        const int b = bh >> 4, h = bh & 15;
        const int s0 = st * 64;

        for (int c = tid; c < 64 * 16; c += 256) {
            int sp = c >> 4, ch = c & 15;
            short8 v = *(const short8*)&kvbb[(size_t)(b * S_ + s0 + sp) * (H_ * 256) + h * 256 + DN + ch * 8];
            union { short8 v; unsigned short u[8]; } t; t.v = v;
            int dv = ch * 8;
#pragma unroll
            for (int e = 0; e < 8; ++e) T[dv + e][sp] = t.u[e];
        }
        __syncthreads();
        for (int c = tid; c < 128 * 8; c += 256) {
            int dv = c >> 3, ch = c & 7;
            *(short8*)&Vt[((size_t)bh * DV + dv) * S_ + s0 + ch * 8] = *(short8*)&T[dv][ch * 8];
        }
    }
}

// ---------------------------------------------------------------------------
// Wave-split dual-tile MFMA flash attention (causal), max-free softmax.
// Block = 512 thr = 8 waves. Waves 0-3 own q-tile qtA=31-bx (full K range);
// waves 4-7 own qtB=bx (prefix of the same range) and share the staged K/V
// tiles -- staging per tile-computation nearly halves, waves/CU doubles.
// ---------------------------------------------------------------------------
#define KROW 200    // 192+8 bf16 pad
#define VROW 72     // 64+8
#define PROW 72
#define NQT 32

__global__ __launch_bounds__(512, 4) void flash_mfma(const unsigned short* __restrict__ Qb,
                                                     const float* __restrict__ fc,
                                                     const unsigned short* __restrict__ Kbf,
                                                     const unsigned short* __restrict__ Vt,
                                                     unsigned short* __restrict__ Ob) {
    __shared__ unsigned short Ks[64][KROW];     // 25600 B
    __shared__ unsigned short Vs[DV][VROW];     // 18432 B
    __shared__ unsigned short Ps[8][16][PROW];  // 18432 B  (total 62464)

    const int bh = blockIdx.x;                  // b*H+h (fast dim -> XCD locality)
    const int bx = blockIdx.y;                  // 0..15 pair index
    const int b = bh >> 4, h = bh & 15;
    const int tid = threadIdx.x;
    const int w = tid >> 6, lane = tid & 63;
    const int l16 = lane & 15, quad = lane >> 4;
    const int ws = w & 3;                       // wave slot within its tile group

    const int qt = (w >= 4) ? bx : (NQT - 1 - bx);
    const int q0 = qt * 64;
    const int myNt = qt + 1;                    // steps this wave computes
    const int ntA = NQT - bx;                   // total staged steps (= qtA+1)

    const unsigned short* Kg = Kbf + (size_t)bh * S_ * DQK;
    const unsigned short* Vg = Vt + (size_t)bh * DV * S_;

    const int s = q0 + ws * 16 + l16;           // this lane's q row (seq pos)

    // Q A-frags from bf16 q, RoPE fused for d >= 128 (pairs are lane-local)
    short8 a_q[6];
    {
        const unsigned short* qrow = Qb + (size_t)(b * S_ + s) * (H_ * DQK) + h * DQK;
#pragma unroll
        for (int i = 0; i < 6; ++i) {
            short8 t = *(const short8*)&qrow[i * 32 + quad * 8];
            if (i >= 4) {
                union { short8 v; unsigned short u[8]; } x; x.v = t;
#pragma unroll
                for (int j = 0; j < 4; ++j) {
                    int ip = (i - 4) * 16 + quad * 4 + j;
                    float c0 = fc[(s * 32 + ip) * 2 + 0];
                    float s0 = fc[(s * 32 + ip) * 2 + 1];
                    float x0 = bf2f(x.u[2 * j]);
                    float x1 = bf2f(x.u[2 * j + 1]);
                    x.u[2 * j]     = f2bf(x0 * c0 - x1 * s0);
                    x.u[2 * j + 1] = f2bf(x0 * s0 + x1 * c0);
                }
                t = x.v;
            }
            a_q[i] = t;
        }
    }

    const float4v zf = {0.f, 0.f, 0.f, 0.f};
    float4v o_acc[8] = {zf, zf, zf, zf, zf, zf, zf, zf};
    float l_r[4] = {0.f, 0.f, 0.f, 0.f};

    // preload tile 0 into registers (staging spread over 512 threads)
    short8 ldK[3], ldV[2];
#pragma unroll
    for (int i = 0; i < 3; ++i) {
        int c = tid + i * 512;
        int r = c / 24, cc = c % 24;
        ldK[i] = *(const short8*)&Kg[(size_t)r * DQK + cc * 8];
    }
#pragma unroll
    for (int i = 0; i < 2; ++i) {
        int c = tid + i * 512;
        int r = c >> 3, cc = c & 7;
        ldV[i] = *(const short8*)&Vg[(size_t)r * S_ + cc * 8];
    }

    for (int kt = 0; kt < ntA; ++kt) {
        const int kbase = kt * 64;
        const bool active = (kt < myNt);
        __syncthreads();   // previous PV done; LDS free
#pragma unroll
        for (int i = 0; i < 3; ++i) {
            int c = tid + i * 512;
            int r = c / 24, cc = c % 24;
            *(short8*)&Ks[r][cc * 8] = ldK[i];
        }
#pragma unroll
        for (int i = 0; i < 2; ++i) {
            int c = tid + i * 512;
            int r = c >> 3, cc = c & 7;
            *(short8*)&Vs[r][cc * 8] = ldV[i];
        }
        if (kt + 1 < ntA) {
            const int kb2 = kbase + 64;
#pragma unroll
            for (int i = 0; i < 3; ++i) {
                int c = tid + i * 512;
                int r = c / 24, cc = c % 24;
                ldK[i] = *(const short8*)&Kg[(size_t)(kb2 + r) * DQK + cc * 8];
            }
#pragma unroll
            for (int i = 0; i < 2; ++i) {
                int c = tid + i * 512;
                int r = c >> 3, cc = c & 7;
                ldV[i] = *(const short8*)&Vg[(size_t)r * S_ + kb2 + cc * 8];
            }
        }
        __syncthreads();   // tile ready

        if (active) {
            // QK^T
            float4v sc[4] = {zf, zf, zf, zf};
#pragma unroll
            for (int kg = 0; kg < 4; ++kg) {
#pragma unroll
                for (int i = 0; i < 6; ++i) {
                    short8 bk = *(const short8*)&Ks[kg * 16 + l16][i * 32 + quad * 8];
                    sc[kg] = __builtin_amdgcn_mfma_f32_16x16x32_bf16(a_q[i], bk, sc[kg], 0, 0, 0);
                }
            }

            // max-free softmax; mask only on the diagonal tile
            const bool diag = (kt == qt);
#pragma unroll
            for (int kg = 0; kg < 4; ++kg) {
                int key = kbase + kg * 16 + l16;
#pragma unroll
                for (int r = 0; r < 4; ++r) {
                    float sv = sc[kg][r] * SCALEF;
                    if (diag && key > q0 + ws * 16 + quad * 4 + r) sv = -1e30f;
                    float p = __expf(sv);
                    l_r[r] += p;
                    Ps[w][quad * 4 + r][kg * 16 + l16] = f2bf(p);
                }
            }
        }

        __syncthreads();   // P writes visible before A-frag reads

        if (active) {
            // PV
#pragma unroll
            for (int kc = 0; kc < 2; ++kc) {
                short8 pa = *(const short8*)&Ps[w][l16][kc * 32 + quad * 8];
#pragma unroll
                for (int dvt = 0; dvt < 8; ++dvt) {
                    short8 vb = *(const short8*)&Vs[dvt * 16 + l16][kc * 32 + quad * 8];
                    o_acc[dvt] = __builtin_amdgcn_mfma_f32_16x16x32_bf16(pa, vb, o_acc[dvt], 0, 0, 0);
                }
            }
        }
    }

    // epilogue: reduce l once, write O
#pragma unroll
    for (int r = 0; r < 4; ++r) {
        float t = l_r[r];
        t += __shfl_xor(t, 1);
        t += __shfl_xor(t, 2);
        t += __shfl_xor(t, 4);
        t += __shfl_xor(t, 8);
        l_r[r] = t;
    }
#pragma unroll
    for (int r = 0; r < 4; ++r) {
        float inv = 1.f / l_r[r];
        int row = q0 + ws * 16 + quad * 4 + r;
        unsigned short* op = Ob + (size_t)(b * S_ + row) * (H_ * DV) + h * DV;
#pragma unroll
        for (int dvt = 0; dvt < 8; ++dvt)
            op[dvt * 16 + l16] = f2bf(o_acc[dvt][r] * inv);
    }
}

// ---------------------------------------------------------------------------
extern "C" void kernel_launch(void* const* d_in, const int* in_sizes, int n_in,
                              void* d_out, int out_size, void* d_ws, size_t ws_size,
                              hipStream_t stream) {
    const float* x    = (const float*)d_in[0];
    const float* fc   = (const float*)d_in[1];
    const float* Wqa  = (const float*)d_in[2];
    const float* qlw  = (const float*)d_in[3];
    const float* Wqb  = (const float*)d_in[4];
    const float* Wkva = (const float*)d_in[5];
    const float* kvw  = (const float*)d_in[6];
    const float* Wkvb = (const float*)d_in[7];
    const float* Wo   = (const float*)d_in[8];
    float* out = (float*)d_out;

    const int M = B_ * S_;                 // 4096
    const int NQKV = QLORA + 640;          // 2176
    char* wsb = (char*)d_ws;

    // R1 (50331648 B): qb bf16 (25165824) + Wob (8388608) + kpe (1048576)
    unsigned short* qb  = (unsigned short*)wsb;
    unsigned short* Wob = (unsigned short*)(wsb + 25165824);
    float*          kpe = (float*)(wsb + 33554432);
    // R2 (67108864 B)
    char* R2 = wsb + 50331648;
    float*          qlkv  = (float*)R2;                          // 35651584
    unsigned short* xb    = (unsigned short*)(R2 + 35651584);    // 16777216
    unsigned short* Wcat  = (unsigned short*)(R2 + 52428800);    //  8912896
    unsigned short* kvbb  = (unsigned short*)R2;                 // 33554432 (after qlkv dead)
    unsigned short* attnb = (unsigned short*)R2;                 // 16777216 (after packs)
    // R3 (25165824 B)
    char* R3 = R2 + 67108864;
    unsigned short* qlatb = (unsigned short*)R3;                 // 12582912
    unsigned short* Wqbb  = (unsigned short*)(R3 + 12582912);    //  9437184
    unsigned short* Kbf   = (unsigned short*)R3;                 // 25165824 (after q-gemm)
    // R4 (16777216 B)
    char* R4 = R3 + 25165824;
    unsigned short* kvcb  = (unsigned short*)R4;                 //  4194304
    unsigned short* Wkvbb = (unsigned short*)(R4 + 4194304);     //  4194304
    unsigned short* Vt    = (unsigned short*)R4;                 // 16777216 (after kvb-gemm)

    // 0) single mega-conversion: x, Wqa, Wkva, Wqb, Wkvb, Wo
    {
        const long e0 = 1048576;           // x      (M*D/8)
        const long e1 = e0 + 393216;       // Wqa
        const long e2 = e1 + 147456;       // Wkva
        const long e3 = e2 + 589824;       // Wqb
        const long e4 = e3 + 262144;       // Wkvb
        const long tot = e4 + 524288;      // Wo
        conv_all<<<(int)(tot / 256), 256, 0, stream>>>(
            x, xb, e0,
            Wqa, Wcat, e1,
            Wkva, Wcat + (size_t)QLORA * D_, e2,
            Wqb, Wqbb, e3,
            Wkvb, Wkvbb, e4,
            Wo, Wob);
    }

    // 1) merged: qlkv = xb @ Wcat^T
    gemm_t<float><<<dim3(NQKV / GBN, M / GBM), 256, 0, stream>>>(xb, Wcat, qlkv, M, NQKV, D_);

    // 2) norms (emit bf16) + k_pe rope
    rmsnorm_b<<<M, 256, 0, stream>>>(qlkv, qlw, qlatb, QLORA, NQKV);
    kv_post<<<M, 256, 0, stream>>>(qlkv + QLORA, kvw, fc, kvcb, kpe, NQKV);

    // 3) qb = qlatb @ Wqbb^T (bf16; RoPE fused into flash) ; kvbb = kvcb @ Wkvbb^T
    gemm_t<unsigned short><<<dim3(H_ * DQK / GBN, M / GBM), 256, 0, stream>>>(qlatb, Wqbb, qb, M, H_ * DQK, QLORA);
    gemm_t<unsigned short><<<dim3(H_ * 256 / GBN, M / GBM), 256, 0, stream>>>(kvcb, Wkvbb, kvbb, M, H_ * 256, KVLORA);

    // 4) fused pack K + V^T
    pack_kv<<<NPK + 1024, 256, 0, stream>>>(kvbb, kpe, Kbf, Vt);

    // 5) wave-split dual-tile flash (x = bh for XCD L2 locality, y = pair)
    flash_mfma<<<dim3(B_ * H_, NQT / 2), 512, 0, stream>>>(qb, fc, Kbf, Vt, attnb);

    // 6) out = attnb @ Wob^T
    gemm_t<float><<<dim3(D_ / GBN, M / GBM), 256, 0, stream>>>(attnb, Wob, out, M, D_, D_);
}